// Round 4
// baseline (162.693 us; speedup 1.0000x reference)
//
#include <hip/hip_runtime.h>
#include <math.h>

#define BB 64
#define II 1024
#define HH 1024

typedef float f4 __attribute__((ext_vector_type(4)));

// ws layout (floats)
#define WS_I     0
#define WS_F     64
#define WS_INVN  128
#define WS_DENOM 192
#define WS_O     256
#define WS_K     (256 + 65536)
#define WS_V     (256 + 2*65536)
#define WS_Q     (256 + 3*65536)

// async global->LDS, 16B per lane; LDS dest is wave-uniform base + lane*16
__device__ __forceinline__ void gll16(const float* g, float* l) {
    __builtin_amdgcn_global_load_lds(
        (const __attribute__((address_space(1))) unsigned int*)g,
        (__attribute__((address_space(3))) unsigned int*)l, 16, 0, 0);
}

// ---------------- kernel 1: per-batch gates + input norm ----------------
__global__ __launch_bounds__(64) void k_gates(const float* __restrict__ input,
                                              const float* __restrict__ if_w,
                                              const float* __restrict__ if_b,
                                              float* __restrict__ ws) {
    int b = blockIdx.x;
    int lane = threadIdx.x;
    const float4* x4 = (const float4*)(input + (size_t)b * II);
    const float4* w0 = (const float4*)(if_w);
    const float4* w1 = (const float4*)(if_w + II);
    float d0 = 0.f, d1 = 0.f, ss = 0.f;
#pragma unroll
    for (int j = 0; j < 4; ++j) {
        int idx = lane + j * 64;
        float4 xv = x4[idx];
        float4 a = w0[idx];
        float4 c = w1[idx];
        d0 += xv.x*a.x + xv.y*a.y + xv.z*a.z + xv.w*a.w;
        d1 += xv.x*c.x + xv.y*c.y + xv.z*c.z + xv.w*c.w;
        ss += xv.x*xv.x + xv.y*xv.y + xv.z*xv.z + xv.w*xv.w;
    }
#pragma unroll
    for (int off = 32; off > 0; off >>= 1) {
        d0 += __shfl_xor(d0, off);
        d1 += __shfl_xor(d1, off);
        ss += __shfl_xor(ss, off);
    }
    if (lane == 0) {
        ws[WS_I + b]    = expf(d0 + if_b[0]);
        ws[WS_F + b]    = expf(d1 + if_b[1]);
        ws[WS_INVN + b] = 1.0f / sqrtf(ss);
    }
}

// ---------------- kernel 2: blocked o/k/v/q projections (+ n update) ----------------
// (unchanged this round — weights read exactly once, lane = batch)
__global__ __launch_bounds__(512) void k_proj(const float* __restrict__ input,
                                              const float* __restrict__ o_w,
                                              const float* __restrict__ kvq_w,
                                              const float* __restrict__ o_b,
                                              const float* __restrict__ kvq_b,
                                              const float* __restrict__ prev_n,
                                              float* __restrict__ ws,
                                              float* __restrict__ n_out) {
    __shared__ float xl[64 * 512];          // 128 KB
    float4* xl4 = (float4*)xl;
    const float4* in4 = (const float4*)input;

    int t = threadIdx.x;
    int wave = t >> 6, lane = t & 63;
    int gr0 = blockIdx.x * 16 + wave * 2;
    const float* wb0 = (gr0 < HH) ? (o_w + (size_t)gr0 * II)
                                  : (kvq_w + (size_t)(gr0 - HH) * II);
    const float* wb1 = wb0 + II;

    float acc0 = 0.f, acc1 = 0.f;
    int sw = lane & 7;

    for (int h = 0; h < 2; ++h) {
        if (h) __syncthreads();
#pragma unroll
        for (int j = 0; j < 16; ++j) {
            int e4 = t + j * 512;
            int b  = e4 >> 7;
            int kq = e4 & 127;
            float4 v = in4[b * 256 + h * 128 + kq];
            xl4[b * 128 + (kq ^ (b & 7))] = v;
        }
        __syncthreads();

        const float4* w40 = (const float4*)(wb0 + h * 512);
        const float4* w41 = (const float4*)(wb1 + h * 512);
        const float4* xb  = xl4 + lane * 128;
#pragma unroll 8
        for (int q = 0; q < 128; ++q) {
            float4 xv = xb[q ^ sw];
            float4 w0 = w40[q];
            float4 w1 = w41[q];
            acc0 += w0.x*xv.x + w0.y*xv.y + w0.z*xv.z + w0.w*xv.w;
            acc1 += w1.x*xv.x + w1.y*xv.y + w1.z*xv.z + w1.w*xv.w;
        }
    }

    float invn = ws[WS_INVN + lane];
    float fb   = ws[WS_F + lane];
    float ib   = ws[WS_I + lane];
#pragma unroll
    for (int r = 0; r < 2; ++r) {
        int gr = gr0 + r;
        float d = r ? acc1 : acc0;
        if (gr < HH) {
            ws[WS_O + lane * HH + gr] = 1.0f / (1.0f + expf(-(d + o_b[gr])));
        } else {
            int wk = gr - HH;
            int which = wk >> 10;
            int hh = wk & 1023;
            float dn = d * invn;
            if (which == 0) {
                float kv = dn * 0.03125f + kvq_b[hh];
                ws[WS_K + lane * HH + hh] = kv;
                n_out[lane * HH + hh] = fb * prev_n[lane * HH + hh] + ib * kv;
            } else if (which == 1) {
                ws[WS_V + lane * HH + hh] = dn + kvq_b[HH + hh];
            } else {
                ws[WS_Q + lane * HH + hh] = dn + kvq_b[2 * HH + hh];
            }
        }
    }
}

// ---------------- kernel 3: denom = max(|n.q|, 1) per batch ----------------
__global__ __launch_bounds__(256) void k_denom(const float* __restrict__ n_out,
                                               float* __restrict__ ws) {
    int b = blockIdx.x;
    int t = threadIdx.x;
    int wave = t >> 6, lane = t & 63;
    const float* nb = n_out + (size_t)b * HH;
    const float* qb = ws + WS_Q + (size_t)b * HH;
    float s = 0.f;
    for (int idx = t; idx < HH; idx += 256) s += nb[idx] * qb[idx];
#pragma unroll
    for (int off = 32; off > 0; off >>= 1) s += __shfl_xor(s, off);
    __shared__ float red[4];
    if (lane == 0) red[wave] = s;
    __syncthreads();
    if (t == 0) {
        float tot = red[0] + red[1] + red[2] + red[3];
        ws[WS_DENOM + b] = fmaxf(fabsf(tot), 1.0f);
    }
}

// ---------------- kernel 4: c update + fused readout h ----------------
// Block = 256 threads (4 waves) owns 32 rows of one batch.
// k,q staged once in LDS (8 KB); prev_c streamed through LDS via
// global_load_lds in 16 KB chunks (4 rows), double-buffered (T3 2-phase).
// grid = 2048 blocks; LDS 40 KB -> 4 blocks/CU; in-flight reads
// 4 x 16 KB per CU >> BW*latency (~4.6 KB) -> read latency decoupled.
__global__ __launch_bounds__(256) void k_cup(const float* __restrict__ prev_c,
                                             const float* __restrict__ ws,
                                             float* __restrict__ c_out,
                                             float* __restrict__ h_out) {
    __shared__ float kq[2048];          // k: floats 0..1023, q: 1024..2047
    __shared__ float cbuf[2][4096];     // two 4-row chunks

    int t = threadIdx.x;
    int wave = t >> 6, lane = t & 63;
    int b = blockIdx.x >> 5;
    int r0 = (blockIdx.x & 31) << 5;                        // local row base
    size_t gbase = ((size_t)b << 20) + ((size_t)r0 << 10);  // float idx of row r0

    const float* kp = ws + WS_K + (size_t)b * HH;
    const float* qp = ws + WS_Q + (size_t)b * HH;

    // prologue: stage k, q (1 gll each per thread) and chunk 0 (4 gll)
    gll16(kp + 4 * t, kq + 4 * t);            // k -> kq[0..1023]
    gll16(qp + 4 * t, kq + 1024 + 4 * t);     // q -> kq[1024..2047]
#pragma unroll
    for (int i = 0; i < 4; ++i) {
        int slot = t + i * 256;
        gll16(prev_c + gbase + 4 * slot, cbuf[0] + 4 * slot);
    }
    __syncthreads();

    float fb = ws[WS_F + b], ib = ws[WS_I + b];
    float inv_d = 1.0f / ws[WS_DENOM + b];

    int buf = 0;
    for (int tc = 0; tc < 8; ++tc) {
        if (tc < 7) {                                       // issue next chunk
            const float* src = prev_c + gbase + ((size_t)(tc + 1) << 12);
#pragma unroll
            for (int i = 0; i < 4; ++i) {
                int slot = t + i * 256;
                gll16(src + 4 * slot, cbuf[buf ^ 1] + 4 * slot);
            }
        }
        int g = (b << 10) + r0 + (tc << 2) + wave;          // global row id
        float iv = ib * ws[WS_V + g];
        float og = ws[WS_O + g];
        const f4* pr = (const f4*)(cbuf[buf]) + wave * 256;
        const f4* k4 = (const f4*)kq;
        const f4* q4 = (const f4*)kq + 256;
        f4* co = (f4*)(c_out + ((size_t)g << 10));
        float s = 0.f;
#pragma unroll
        for (int j = 0; j < 4; ++j) {
            int idx = lane + j * 64;
            f4 p = pr[idx], kv = k4[idx], qv = q4[idx];
            f4 c;
            c.x = fb * p.x + iv * kv.x;
            c.y = fb * p.y + iv * kv.y;
            c.z = fb * p.z + iv * kv.z;
            c.w = fb * p.w + iv * kv.w;
            co[idx] = c;
            s += c.x * qv.x + c.y * qv.y + c.z * qv.z + c.w * qv.w;
        }
#pragma unroll
        for (int off = 32; off > 0; off >>= 1) s += __shfl_xor(s, off);
        if (lane == 0) h_out[g] = og * s * inv_d;
        __syncthreads();                                    // drains gll for tc+1
        buf ^= 1;
    }
}

extern "C" void kernel_launch(void* const* d_in, const int* in_sizes, int n_in,
                              void* d_out, int out_size, void* d_ws, size_t ws_size,
                              hipStream_t stream) {
    const float* input  = (const float*)d_in[0];
    const float* prev_c = (const float*)d_in[2];
    const float* prev_n = (const float*)d_in[3];
    const float* if_w   = (const float*)d_in[4];
    const float* o_w    = (const float*)d_in[5];
    const float* kvq_w  = (const float*)d_in[6];
    const float* if_b   = (const float*)d_in[7];
    const float* o_b    = (const float*)d_in[8];
    const float* kvq_b  = (const float*)d_in[9];

    float* out   = (float*)d_out;
    float* h_out = out;                          // [B,H]
    float* c_out = out + 65536;                  // [B,H,H]
    float* n_out = out + 65536 + 67108864;       // [B,H]
    float* ws    = (float*)d_ws;

    k_gates<<<BB, 64, 0, stream>>>(input, if_w, if_b, ws);
    k_proj <<<256, 512, 0, stream>>>(input, o_w, kvq_w, o_b, kvq_b, prev_n, ws, n_out);
    k_denom<<<BB, 256, 0, stream>>>(n_out, ws);
    k_cup  <<<2048, 256, 0, stream>>>(prev_c, ws, c_out, h_out);
}